// Round 20
// baseline (170.091 us; speedup 1.0000x reference)
//
#include <hip/hip_runtime.h>

#define N_NODESC 100000
#define N_EDGESC 10000
#define N_PAIRSC 1600000
#define FDIM 128

#define NB 200       // buckets per path
#define EPB 50       // edges per bucket  (200*50 = 10000)
#define NPB 500      // nodes per bucket  (200*500 = 100000)
#define ECAP2 8704   // fixed bucket stride; mean 8000, sigma 89 -> 7.9 sigma slack
#define PA_CHUNK 4096
#define PA_NCH ((N_PAIRSC + PA_CHUNK - 1) / PA_CHUNK)  // 391
#define MSG_BLKS 782

typedef short bf16x8 __attribute__((ext_vector_type(8)));
typedef float f32x4 __attribute__((ext_vector_type(4)));
typedef float f32x2 __attribute__((ext_vector_type(2)));
typedef int i32x4 __attribute__((ext_vector_type(4)));
typedef unsigned u32x4 __attribute__((ext_vector_type(4)));

__device__ __forceinline__ unsigned short f2b(float f) {
  unsigned u = __float_as_uint(f);
  u += 0x7fffu + ((u >> 16) & 1u);
  return (unsigned short)(u >> 16);
}
__device__ __forceinline__ float b2f(unsigned short b) {
  return __uint_as_float(((unsigned)b) << 16);
}
__device__ __forceinline__ unsigned pack2(float a, float b) {
  return (unsigned)f2b(a) | ((unsigned)f2b(b) << 16);
}
// tanh-form gelu: z*e/(e+1), e=exp(1.59576912*z*(1+0.044715 z^2)). |diff| <= ~1e-3.
__device__ __forceinline__ float gelu_fast(float z) {
  float z2 = z * z;
  float w = fmaf(0.044715f, z2, 1.0f);
  float e = __expf(1.5957691216f * z * w);
  return z * e * __builtin_amdgcn_rcpf(e + 1.0f);
}
// load 8 consecutive f32 from row, convert to bf16x8 fragment
__device__ __forceinline__ bf16x8 ldA(const float* p) {
  float4 u0 = *(const float4*)p;
  float4 u1 = *(const float4*)(p + 4);
  u32x4 w = {pack2(u0.x, u0.y), pack2(u0.z, u0.w), pack2(u1.x, u1.y), pack2(u1.z, u1.w)};
  return __builtin_bit_cast(bf16x8, w);
}

// ---------------- prep: weights -> bf16, send/recv, bucket cursor init ----------------
__global__ __launch_bounds__(256) void k_prep(const float* __restrict__ action,
                                              const float* __restrict__ wmsg, const float* __restrict__ wupd,
                                              short* __restrict__ wmsgb, short* __restrict__ wupdb,
                                              float* __restrict__ send, float* __restrict__ recv,
                                              int* __restrict__ gcure, int* __restrict__ gcurn) {
  int i = blockIdx.x * 256 + threadIdx.x;
  if (i < FDIM * FDIM) {
    wmsgb[i] = (short)f2b(wmsg[i]);
    wupdb[i] = (short)f2b(wupd[i]);
  }
  if (i < N_NODESC) {
    float a0 = action[i * 3 + 0], a1 = action[i * 3 + 1], a2 = action[i * 3 + 2];
    send[i] = a0 + a2;
    recv[i] = a0 + a1;
  }
  if (i < NB) {
    gcure[i] = i * ECAP2;
    gcurn[i] = i * ECAP2;
  }
}

// ---------------- scan helper ----------------
__device__ __forceinline__ int wave_incl_scan(int v, int lane) {
#pragma unroll
  for (int d = 1; d < 64; d <<= 1) {
    int n = __shfl_up(v, d, 64);
    if (lane >= d) v += n;
  }
  return v;
}

// ---------------- fused: E-part (0..390) || N-part (391..781) || gemm_msg (782..1563) ----------------
// Partition block sorts ONE path's 4096-item chunk through a 16KB LDS buffer.
// Total LDS ~20KB keeps 8 blocks/CU for ALL blocks (incl. the GEMM majority) -
// the 36KB variant capped everyone at 4 blocks/CU (R19's hidden occupancy tax).
__global__ __launch_bounds__(256) void k_part_msg(const int* __restrict__ pn, const int* __restrict__ pe,
                                                  int* __restrict__ gcure, int* __restrict__ gcurn,
                                                  unsigned* __restrict__ buckE, unsigned* __restrict__ buckN,
                                                  const float* __restrict__ x, const short* __restrict__ wb,
                                                  const float* __restrict__ send,
                                                  unsigned char* __restrict__ mji8) {
  __shared__ unsigned ordered[PA_CHUNK];                       // 16 KB
  __shared__ int cb[NB], ls[NB], cur[NB], gb[NB];              // 3.2 KB
  int t = threadIdx.x;
  if (blockIdx.x < 2 * PA_NCH) {
    int isN = blockIdx.x >= PA_NCH;
    int blk = isN ? (int)blockIdx.x - PA_NCH : (int)blockIdx.x;
    int* gcur = isN ? gcurn : gcure;
    unsigned* buck = isN ? buckN : buckE;
    long long base = (long long)blk * PA_CHUNK;
    int nItems = (int)(((long long)N_PAIRSC - base) < PA_CHUNK ? (N_PAIRSC - base) : PA_CHUNK);
    for (int i = t; i < NB; i += 256) cb[i] = 0;
    __syncthreads();
    // pass 1: count
    for (int q = t; q < PA_CHUNK / 4; q += 256) {
      long long idx = base + (long long)q * 4;
      if (idx >= N_PAIRSC) break;
      i32x4 k4 = __builtin_nontemporal_load((const i32x4*)((isN ? pn : pe) + idx));
#pragma unroll
      for (int j = 0; j < 4; j++) {
        int b = isN ? (k4[j] / NPB) : (k4[j] / EPB);
        atomicAdd(&cb[b], 1);
      }
    }
    __syncthreads();
    // scan (wave 0) -> block-local exclusive offsets
    if (t < 64) {
      int carry = 0;
      for (int b0 = 0; b0 < NB; b0 += 64) {
        int idx = b0 + t;
        int v = (idx < NB) ? cb[idx] : 0;
        int inc = wave_incl_scan(v, t);
        if (idx < NB) ls[idx] = carry + inc - v;
        carry += __shfl(inc, 63, 64);
      }
    }
    __syncthreads();
    if (t < NB) {
      gb[t] = atomicAdd(&gcur[t], cb[t]);
      cur[t] = ls[t];
    }
    __syncthreads();
    // pass 2: re-read globals, order bucket-major into LDS
    for (int q = t; q < PA_CHUNK / 4; q += 256) {
      long long idx = base + (long long)q * 4;
      if (idx >= N_PAIRSC) break;
      i32x4 e4 = __builtin_nontemporal_load((const i32x4*)(pe + idx));
      i32x4 v4 = __builtin_nontemporal_load((const i32x4*)(pn + idx));
#pragma unroll
      for (int j = 0; j < 4; j++) {
        unsigned ee = (unsigned)e4[j], vv = (unsigned)v4[j];
        unsigned u = isN ? ((vv << 14) | ee) : ((ee << 17) | vv);
        int b = isN ? (int)(vv / NPB) : (int)(ee / EPB);
        int pos = atomicAdd(&cur[b], 1);
        ordered[pos] = u;
      }
    }
    __syncthreads();
    // pass 3: coalesced copy-out
    int shift = isN ? 14 : 17;
    for (int i = t; i < nItems; i += 256) {
      unsigned u = ordered[i];
      int b = isN ? (int)((u >> shift) / NPB) : (int)((u >> shift) / EPB);
      buck[gb[b] + (i - ls[b])] = u;
    }
  } else {
    // ---- gemm_msg path ----
    int gw = ((int)(blockIdx.x - 2 * PA_NCH) * 256 + t) >> 6;
    int lane = t & 63;
    if (gw >= N_NODESC / 32) return;
    int rb = gw * 32;
    int lr = lane & 15, lg = lane >> 4;

    bf16x8 A0[4], A1[4];
    const float* xrow0 = x + (size_t)(rb + lr) * FDIM + lg * 8;
    const float* xrow1 = xrow0 + 16 * FDIM;
#pragma unroll
    for (int kk = 0; kk < 4; kk++) {
      A0[kk] = ldA(xrow0 + kk * 32);
      A1[kk] = ldA(xrow1 + kk * 32);
    }
    float sv0[4], sv1[4];
#pragma unroll
    for (int j = 0; j < 4; j++) {
      sv0[j] = send[rb + lg * 4 + j];
      sv1[j] = send[rb + 16 + lg * 4 + j];
    }
#pragma unroll
    for (int c = 0; c < 8; c++) {
      f32x4 acc0 = {0.f, 0.f, 0.f, 0.f}, acc1 = {0.f, 0.f, 0.f, 0.f};
      const short* wrow = wb + (size_t)(16 * c + lr) * FDIM + lg * 8;
#pragma unroll
      for (int kk = 0; kk < 4; kk++) {
        bf16x8 B = *(const bf16x8*)(wrow + kk * 32);
        acc0 = __builtin_amdgcn_mfma_f32_16x16x32_bf16(A0[kk], B, acc0, 0, 0, 0);
        acc1 = __builtin_amdgcn_mfma_f32_16x16x32_bf16(A1[kk], B, acc1, 0, 0, 0);
      }
      int col = 16 * c + lr;
#pragma unroll
      for (int j = 0; j < 4; j++) {
        float m0 = gelu_fast(acc0[j]) * sv0[j];
        float m1 = gelu_fast(acc1[j]) * sv1[j];
        int row0 = rb + lg * 4 + j;
        mji8[(size_t)row0 * FDIM + col] =
            (unsigned char)(__builtin_amdgcn_cvt_pk_fp8_f32(m0, m0, 0, false) & 0xFF);
        mji8[(size_t)(row0 + 16) * FDIM + col] =
            (unsigned char)(__builtin_amdgcn_cvt_pk_fp8_f32(m1, m1, 0, false) & 0xFF);
      }
    }
  }
}

// ---------------- fine_E: per-edge counts/offsets + sorted sn ----------------
__global__ __launch_bounds__(256) void k_fine_e(const unsigned* __restrict__ buckE,
                                                const int* __restrict__ gcure,
                                                int* __restrict__ ecnt, int* __restrict__ eoff,
                                                int* __restrict__ sn) {
  __shared__ int cnt_s[EPB], cur_s[EPB];
  int b = blockIdx.x, t = threadIdx.x;
  int lo = b * EPB, beg = b * ECAP2, end = gcure[b];
  if (t < EPB) cnt_s[t] = 0;
  __syncthreads();
  for (int i = beg + t; i < end; i += 256)
    atomicAdd(&cnt_s[(int)(buckE[i] >> 17) - lo], 1);
  __syncthreads();
  if (t < 64) {
    int v = (t < EPB) ? cnt_s[t] : 0;
    int inc = wave_incl_scan(v, t);
    if (t < EPB) cur_s[t] = beg + inc - v;
  }
  __syncthreads();
  if (t < EPB) {
    ecnt[lo + t] = cnt_s[t];
    eoff[lo + t] = cur_s[t];
  }
  __syncthreads();
  for (int i = beg + t; i < end; i += 256) {
    unsigned u = buckE[i];
    int key = (int)(u >> 17) - lo;
    int pos = atomicAdd(&cur_s[key], 1);
    sn[pos] = (int)(u & 0x1FFFF);
  }
}

// ---------------- fused: fine_N (blocks 0..199)  ||  k_edge (blocks 200..1449) ----------------
__global__ __launch_bounds__(256) void k_edge_fineN(const unsigned* __restrict__ buckN,
                                                    const int* __restrict__ gcurn,
                                                    int* __restrict__ ncnt, int* __restrict__ noff,
                                                    int* __restrict__ se,
                                                    const unsigned char* __restrict__ mji8,
                                                    const int* __restrict__ sn,
                                                    const int* __restrict__ eoff, const int* __restrict__ ecnt,
                                                    unsigned char* __restrict__ efeat8) {
  __shared__ int cnt_s[NPB], cur_s[NPB];
  int t = threadIdx.x;
  if (blockIdx.x < NB) {
    // ---- fine_N path ----
    int b = blockIdx.x;
    int lo = b * NPB, beg = b * ECAP2, end = gcurn[b];
    for (int i = t; i < NPB; i += 256) cnt_s[i] = 0;
    __syncthreads();
    for (int i = beg + t; i < end; i += 256)
      atomicAdd(&cnt_s[(int)(buckN[i] >> 14) - lo], 1);
    __syncthreads();
    if (t < 64) {
      int carry = beg;
#pragma unroll
      for (int base = 0; base < NPB; base += 64) {
        int idx = base + t;
        int v = (idx < NPB) ? cnt_s[idx] : 0;
        int inc = wave_incl_scan(v, t);
        if (idx < NPB) cur_s[idx] = carry + inc - v;
        carry += __shfl(inc, 63, 64);
      }
    }
    __syncthreads();
    for (int i = t; i < NPB; i += 256) {
      ncnt[lo + i] = cnt_s[i];
      noff[lo + i] = cur_s[i];
    }
    __syncthreads();
    for (int i = beg + t; i < end; i += 256) {
      unsigned u = buckN[i];
      int key = (int)(u >> 14) - lo;
      int pos = atomicAdd(&cur_s[key], 1);
      se[pos] = (int)(u & 0x3FFF);
    }
  } else {
    // ---- edge path ----
    int wave = (int)(blockIdx.x - NB) * 4 + (t >> 6);
    int lane = t & 63;
    int half = lane >> 5, sub2 = (lane >> 4) & 1, c4 = lane & 15;
    int edge = wave * 2 + half;
    if (edge >= N_EDGESC) return;
    int beg = eoff[edge], cnt = ecnt[edge];
    f32x2 a0 = {0.f, 0.f}, a1 = {0.f, 0.f}, a2 = {0.f, 0.f}, a3 = {0.f, 0.f};
#pragma unroll 4
    for (int p = sub2; p < cnt; p += 2) {
      int node = sn[beg + p];
      uint2 u = ((const uint2*)(mji8 + (size_t)node * FDIM))[c4];
      a0 += __builtin_amdgcn_cvt_pk_f32_fp8(u.x, false);
      a1 += __builtin_amdgcn_cvt_pk_f32_fp8(u.x, true);
      a2 += __builtin_amdgcn_cvt_pk_f32_fp8(u.y, false);
      a3 += __builtin_amdgcn_cvt_pk_f32_fp8(u.y, true);
    }
    a0[0] += __shfl_xor(a0[0], 16, 64); a0[1] += __shfl_xor(a0[1], 16, 64);
    a1[0] += __shfl_xor(a1[0], 16, 64); a1[1] += __shfl_xor(a1[1], 16, 64);
    a2[0] += __shfl_xor(a2[0], 16, 64); a2[1] += __shfl_xor(a2[1], 16, 64);
    a3[0] += __shfl_xor(a3[0], 16, 64); a3[1] += __shfl_xor(a3[1], 16, 64);
    if (sub2 == 0) {
      float inv = 1.0f / fmaxf((float)cnt, 1.0f);
      uint2 o;
      o.x = (unsigned)__builtin_amdgcn_cvt_pk_fp8_f32(a0[0] * inv, a0[1] * inv, 0, false);
      o.x = (unsigned)__builtin_amdgcn_cvt_pk_fp8_f32(a1[0] * inv, a1[1] * inv, (int)o.x, true);
      o.y = (unsigned)__builtin_amdgcn_cvt_pk_fp8_f32(a2[0] * inv, a2[1] * inv, 0, false);
      o.y = (unsigned)__builtin_amdgcn_cvt_pk_fp8_f32(a3[0] * inv, a3[1] * inv, (int)o.y, true);
      ((uint2*)(efeat8 + (size_t)edge * FDIM))[c4] = o;
    }
  }
}

// ---------------- node reduce -> fp8 mi (one node per 16-lane sub) ----------------
__global__ __launch_bounds__(256) void k_node(const unsigned char* __restrict__ efeat8, const int* __restrict__ se,
                                              const int* __restrict__ noff, const int* __restrict__ ncnt,
                                              const float* __restrict__ recv, unsigned char* __restrict__ mi8) {
  int wave = blockIdx.x * 4 + (threadIdx.x >> 6);
  int lane = threadIdx.x & 63;
  int sub = lane >> 4, c4 = lane & 15;
  int node = wave * 4 + sub;   // 25000 waves x 4 = 100000 exactly
  int beg = noff[node], cnt = ncnt[node];
  f32x2 a0 = {0.f, 0.f}, a1 = {0.f, 0.f}, a2 = {0.f, 0.f}, a3 = {0.f, 0.f};
#pragma unroll 4
  for (int p = 0; p < cnt; p++) {
    int e = se[beg + p];
    uint2 u = ((const uint2*)(efeat8 + (size_t)e * FDIM))[c4];
    a0 += __builtin_amdgcn_cvt_pk_f32_fp8(u.x, false);
    a1 += __builtin_amdgcn_cvt_pk_f32_fp8(u.x, true);
    a2 += __builtin_amdgcn_cvt_pk_f32_fp8(u.y, false);
    a3 += __builtin_amdgcn_cvt_pk_f32_fp8(u.y, true);
  }
  float s = recv[node] / fmaxf((float)cnt, 1.0f);
  uint2 o;
  o.x = (unsigned)__builtin_amdgcn_cvt_pk_fp8_f32(a0[0] * s, a0[1] * s, 0, false);
  o.x = (unsigned)__builtin_amdgcn_cvt_pk_fp8_f32(a1[0] * s, a1[1] * s, (int)o.x, true);
  o.y = (unsigned)__builtin_amdgcn_cvt_pk_fp8_f32(a2[0] * s, a2[1] * s, 0, false);
  o.y = (unsigned)__builtin_amdgcn_cvt_pk_fp8_f32(a3[0] * s, a3[1] * s, (int)o.y, true);
  ((uint2*)(mi8 + (size_t)node * FDIM))[c4] = o;
}

// ---------------- GEMM 2: out = gelu(x @ Wupd^T + b + m_i) -> f32, 32 rows/wave ----------------
__global__ __launch_bounds__(256) void k_gemm_upd(const float* __restrict__ x, const short* __restrict__ wb,
                                                  const float* __restrict__ bias,
                                                  const unsigned char* __restrict__ mi8,
                                                  float* __restrict__ out) {
  int gw = (blockIdx.x * 256 + threadIdx.x) >> 6;
  int lane = threadIdx.x & 63;
  if (gw >= N_NODESC / 32) return;
  int rb = gw * 32;
  int lr = lane & 15, lg = lane >> 4;

  bf16x8 A0[4], A1[4];
  const float* xrow0 = x + (size_t)(rb + lr) * FDIM + lg * 8;
  const float* xrow1 = xrow0 + 16 * FDIM;
#pragma unroll
  for (int kk = 0; kk < 4; kk++) {
    A0[kk] = ldA(xrow0 + kk * 32);
    A1[kk] = ldA(xrow1 + kk * 32);
  }

#pragma unroll
  for (int c = 0; c < 8; c++) {
    f32x4 acc0 = {0.f, 0.f, 0.f, 0.f}, acc1 = {0.f, 0.f, 0.f, 0.f};
    const short* wrow = wb + (size_t)(16 * c + lr) * FDIM + lg * 8;
#pragma unroll
    for (int kk = 0; kk < 4; kk++) {
      bf16x8 B = *(const bf16x8*)(wrow + kk * 32);
      acc0 = __builtin_amdgcn_mfma_f32_16x16x32_bf16(A0[kk], B, acc0, 0, 0, 0);
      acc1 = __builtin_amdgcn_mfma_f32_16x16x32_bf16(A1[kk], B, acc1, 0, 0, 0);
    }
    int col = 16 * c + lr;
    float bc = bias[col];
#pragma unroll
    for (int j = 0; j < 4; j++) {
      int row0 = rb + lg * 4 + j;
      f32x2 m0 = __builtin_amdgcn_cvt_pk_f32_fp8((unsigned)mi8[(size_t)row0 * FDIM + col], false);
      f32x2 m1 = __builtin_amdgcn_cvt_pk_f32_fp8((unsigned)mi8[(size_t)(row0 + 16) * FDIM + col], false);
      float z0 = acc0[j] + bc + m0[0];
      float z1 = acc1[j] + bc + m1[0];
      __builtin_nontemporal_store(gelu_fast(z0), &out[(size_t)row0 * FDIM + col]);
      __builtin_nontemporal_store(gelu_fast(z1), &out[(size_t)(row0 + 16) * FDIM + col]);
    }
  }
}

extern "C" void kernel_launch(void* const* d_in, const int* in_sizes, int n_in,
                              void* d_out, int out_size, void* d_ws, size_t ws_size,
                              hipStream_t stream) {
  const float* x = (const float*)d_in[0];
  const float* action = (const float*)d_in[1];
  const float* wmsg = (const float*)d_in[2];
  const float* wupd = (const float*)d_in[3];
  const float* bupd = (const float*)d_in[4];
  const int* pn = (const int*)d_in[5];
  const int* pe = (const int*)d_in[6];
  float* out = (float*)d_out;

  char* p = (char*)d_ws;
  auto alloc = [&](size_t bytes) -> char* {
    char* r = p;
    p += (bytes + 255) & ~(size_t)255;
    return r;
  };
  unsigned char* mji8 = (unsigned char*)alloc((size_t)N_NODESC * FDIM);
  unsigned char* mi8 = (unsigned char*)alloc((size_t)N_NODESC * FDIM);
  unsigned char* efeat8 = (unsigned char*)alloc((size_t)N_EDGESC * FDIM);
  unsigned* buckE = (unsigned*)alloc((size_t)NB * ECAP2 * 4);
  unsigned* buckN = (unsigned*)alloc((size_t)NB * ECAP2 * 4);
  int* sn = (int*)alloc((size_t)NB * ECAP2 * 4);
  int* se = (int*)alloc((size_t)NB * ECAP2 * 4);
  short* wmsgb = (short*)alloc(FDIM * FDIM * 2);
  short* wupdb = (short*)alloc(FDIM * FDIM * 2);
  float* send = (float*)alloc(N_NODESC * 4);
  float* recv = (float*)alloc(N_NODESC * 4);
  int* ecnt = (int*)alloc(N_EDGESC * 4);
  int* eoff = (int*)alloc(N_EDGESC * 4);
  int* ncnt = (int*)alloc(N_NODESC * 4);
  int* noff = (int*)alloc(N_NODESC * 4);
  int* gcure = (int*)alloc(NB * 4);
  int* gcurn = (int*)alloc(NB * 4);

  k_prep<<<391, 256, 0, stream>>>(action, wmsg, wupd, wmsgb, wupdb, send, recv, gcure, gcurn);
  k_part_msg<<<2 * PA_NCH + MSG_BLKS, 256, 0, stream>>>(pn, pe, gcure, gcurn, buckE, buckN,
                                                        x, wmsgb, send, mji8);
  k_fine_e<<<NB, 256, 0, stream>>>(buckE, gcure, ecnt, eoff, sn);
  k_edge_fineN<<<NB + 1250, 256, 0, stream>>>(buckN, gcurn, ncnt, noff, se,
                                              mji8, sn, eoff, ecnt, efeat8);
  k_node<<<6250, 256, 0, stream>>>(efeat8, se, noff, ncnt, recv, mi8);
  k_gemm_upd<<<782, 256, 0, stream>>>(x, wupdb, bupd, mi8, out);
}

// Round 21
// 158.821 us; speedup vs baseline: 1.0710x; 1.0710x over previous
//
#include <hip/hip_runtime.h>

#define N_NODESC 100000
#define N_EDGESC 10000
#define N_PAIRSC 1600000
#define FDIM 128

#define NB 200       // buckets per path
#define EPB 50       // edges per bucket  (200*50 = 10000)
#define NPB 500      // nodes per bucket  (200*500 = 100000)
#define ECAP2 8704   // fixed bucket stride; mean 8000, sigma 89 -> 7.9 sigma slack
#define PA_CHUNK 8192
#define PA_NCH ((N_PAIRSC + PA_CHUNK - 1) / PA_CHUNK)  // 196
#define MSG_BLKS 782

typedef short bf16x8 __attribute__((ext_vector_type(8)));
typedef float f32x4 __attribute__((ext_vector_type(4)));
typedef float f32x2 __attribute__((ext_vector_type(2)));
typedef int i32x4 __attribute__((ext_vector_type(4)));
typedef unsigned u32x4 __attribute__((ext_vector_type(4)));

__device__ __forceinline__ unsigned short f2b(float f) {
  unsigned u = __float_as_uint(f);
  u += 0x7fffu + ((u >> 16) & 1u);
  return (unsigned short)(u >> 16);
}
__device__ __forceinline__ float b2f(unsigned short b) {
  return __uint_as_float(((unsigned)b) << 16);
}
__device__ __forceinline__ unsigned pack2(float a, float b) {
  return (unsigned)f2b(a) | ((unsigned)f2b(b) << 16);
}
// tanh-form gelu: z*e/(e+1), e=exp(1.59576912*z*(1+0.044715 z^2)). |diff| <= ~1e-3.
__device__ __forceinline__ float gelu_fast(float z) {
  float z2 = z * z;
  float w = fmaf(0.044715f, z2, 1.0f);
  float e = __expf(1.5957691216f * z * w);
  return z * e * __builtin_amdgcn_rcpf(e + 1.0f);
}
// load 8 consecutive f32 from row, convert to bf16x8 fragment
__device__ __forceinline__ bf16x8 ldA(const float* p) {
  float4 u0 = *(const float4*)p;
  float4 u1 = *(const float4*)(p + 4);
  u32x4 w = {pack2(u0.x, u0.y), pack2(u0.z, u0.w), pack2(u1.x, u1.y), pack2(u1.z, u1.w)};
  return __builtin_bit_cast(bf16x8, w);
}

// ---------------- prep: weights -> bf16, send/recv, bucket cursor init ----------------
__global__ __launch_bounds__(256) void k_prep(const float* __restrict__ action,
                                              const float* __restrict__ wmsg, const float* __restrict__ wupd,
                                              short* __restrict__ wmsgb, short* __restrict__ wupdb,
                                              float* __restrict__ send, float* __restrict__ recv,
                                              int* __restrict__ gcure, int* __restrict__ gcurn) {
  int i = blockIdx.x * 256 + threadIdx.x;
  if (i < FDIM * FDIM) {
    wmsgb[i] = (short)f2b(wmsg[i]);
    wupdb[i] = (short)f2b(wupd[i]);
  }
  if (i < N_NODESC) {
    float a0 = action[i * 3 + 0], a1 = action[i * 3 + 1], a2 = action[i * 3 + 2];
    send[i] = a0 + a2;
    recv[i] = a0 + a1;
  }
  if (i < NB) {
    gcure[i] = i * ECAP2;
    gcurn[i] = i * ECAP2;
  }
}

// ---------------- scan helper ----------------
__device__ __forceinline__ int wave_incl_scan(int v, int lane) {
#pragma unroll
  for (int d = 1; d < 64; d <<= 1) {
    int n = __shfl_up(v, d, 64);
    if (lane >= d) v += n;
  }
  return v;
}

// ---------------- fused: E-part (0..195) || N-part (196..391) || gemm_msg (392..1173) ----------------
// Each partition block sorts ONE path's chunk: count pass (global read) -> scan ->
// order pass (global re-read, bucket-major into 32KB LDS) -> coalesced copy-out.
__global__ __launch_bounds__(256) void k_part_msg(const int* __restrict__ pn, const int* __restrict__ pe,
                                                  int* __restrict__ gcure, int* __restrict__ gcurn,
                                                  unsigned* __restrict__ buckE, unsigned* __restrict__ buckN,
                                                  const float* __restrict__ x, const short* __restrict__ wb,
                                                  const float* __restrict__ send,
                                                  unsigned char* __restrict__ mji8) {
  __shared__ unsigned ordered[PA_CHUNK];                       // 32 KB
  __shared__ int cb[NB], ls[NB], cur[NB], gb[NB];              // 3.2 KB
  int t = threadIdx.x;
  if (blockIdx.x < 2 * PA_NCH) {
    int isN = blockIdx.x >= PA_NCH;
    int blk = isN ? (int)blockIdx.x - PA_NCH : (int)blockIdx.x;
    int* gcur = isN ? gcurn : gcure;
    unsigned* buck = isN ? buckN : buckE;
    long long base = (long long)blk * PA_CHUNK;
    int nItems = (int)(((long long)N_PAIRSC - base) < PA_CHUNK ? (N_PAIRSC - base) : PA_CHUNK);
    for (int i = t; i < NB; i += 256) cb[i] = 0;
    __syncthreads();
    // pass 1: count
    for (int q = t; q < PA_CHUNK / 4; q += 256) {
      long long idx = base + (long long)q * 4;
      if (idx >= N_PAIRSC) break;
      i32x4 k4 = __builtin_nontemporal_load((const i32x4*)((isN ? pn : pe) + idx));
#pragma unroll
      for (int j = 0; j < 4; j++) {
        int b = isN ? (k4[j] / NPB) : (k4[j] / EPB);
        atomicAdd(&cb[b], 1);
      }
    }
    __syncthreads();
    // scan (wave 0) -> block-local exclusive offsets
    if (t < 64) {
      int carry = 0;
      for (int b0 = 0; b0 < NB; b0 += 64) {
        int idx = b0 + t;
        int v = (idx < NB) ? cb[idx] : 0;
        int inc = wave_incl_scan(v, t);
        if (idx < NB) ls[idx] = carry + inc - v;
        carry += __shfl(inc, 63, 64);
      }
    }
    __syncthreads();
    if (t < NB) {
      gb[t] = atomicAdd(&gcur[t], cb[t]);
      cur[t] = ls[t];
    }
    __syncthreads();
    // pass 2: re-read globals, order bucket-major into LDS
    for (int q = t; q < PA_CHUNK / 4; q += 256) {
      long long idx = base + (long long)q * 4;
      if (idx >= N_PAIRSC) break;
      i32x4 e4 = __builtin_nontemporal_load((const i32x4*)(pe + idx));
      i32x4 v4 = __builtin_nontemporal_load((const i32x4*)(pn + idx));
#pragma unroll
      for (int j = 0; j < 4; j++) {
        unsigned ee = (unsigned)e4[j], vv = (unsigned)v4[j];
        unsigned u = isN ? ((vv << 14) | ee) : ((ee << 17) | vv);
        int b = isN ? (int)(vv / NPB) : (int)(ee / EPB);
        int pos = atomicAdd(&cur[b], 1);
        ordered[pos] = u;
      }
    }
    __syncthreads();
    // pass 3: coalesced copy-out
    int shift = isN ? 14 : 17;
    for (int i = t; i < nItems; i += 256) {
      unsigned u = ordered[i];
      int b = isN ? (int)((u >> shift) / NPB) : (int)((u >> shift) / EPB);
      buck[gb[b] + (i - ls[b])] = u;
    }
  } else {
    // ---- gemm_msg path ----
    int gw = ((int)(blockIdx.x - 2 * PA_NCH) * 256 + t) >> 6;
    int lane = t & 63;
    if (gw >= N_NODESC / 32) return;
    int rb = gw * 32;
    int lr = lane & 15, lg = lane >> 4;

    bf16x8 A0[4], A1[4];
    const float* xrow0 = x + (size_t)(rb + lr) * FDIM + lg * 8;
    const float* xrow1 = xrow0 + 16 * FDIM;
#pragma unroll
    for (int kk = 0; kk < 4; kk++) {
      A0[kk] = ldA(xrow0 + kk * 32);
      A1[kk] = ldA(xrow1 + kk * 32);
    }
    float sv0[4], sv1[4];
#pragma unroll
    for (int j = 0; j < 4; j++) {
      sv0[j] = send[rb + lg * 4 + j];
      sv1[j] = send[rb + 16 + lg * 4 + j];
    }
#pragma unroll
    for (int c = 0; c < 8; c++) {
      f32x4 acc0 = {0.f, 0.f, 0.f, 0.f}, acc1 = {0.f, 0.f, 0.f, 0.f};
      const short* wrow = wb + (size_t)(16 * c + lr) * FDIM + lg * 8;
#pragma unroll
      for (int kk = 0; kk < 4; kk++) {
        bf16x8 B = *(const bf16x8*)(wrow + kk * 32);
        acc0 = __builtin_amdgcn_mfma_f32_16x16x32_bf16(A0[kk], B, acc0, 0, 0, 0);
        acc1 = __builtin_amdgcn_mfma_f32_16x16x32_bf16(A1[kk], B, acc1, 0, 0, 0);
      }
      int col = 16 * c + lr;
#pragma unroll
      for (int j = 0; j < 4; j++) {
        float m0 = gelu_fast(acc0[j]) * sv0[j];
        float m1 = gelu_fast(acc1[j]) * sv1[j];
        int row0 = rb + lg * 4 + j;
        mji8[(size_t)row0 * FDIM + col] =
            (unsigned char)(__builtin_amdgcn_cvt_pk_fp8_f32(m0, m0, 0, false) & 0xFF);
        mji8[(size_t)(row0 + 16) * FDIM + col] =
            (unsigned char)(__builtin_amdgcn_cvt_pk_fp8_f32(m1, m1, 0, false) & 0xFF);
      }
    }
  }
}

// ---------------- fine_E: per-edge counts/offsets + sorted sn ----------------
__global__ __launch_bounds__(256) void k_fine_e(const unsigned* __restrict__ buckE,
                                                const int* __restrict__ gcure,
                                                int* __restrict__ ecnt, int* __restrict__ eoff,
                                                int* __restrict__ sn) {
  __shared__ int cnt_s[EPB], cur_s[EPB];
  int b = blockIdx.x, t = threadIdx.x;
  int lo = b * EPB, beg = b * ECAP2, end = gcure[b];
  if (t < EPB) cnt_s[t] = 0;
  __syncthreads();
  for (int i = beg + t; i < end; i += 256)
    atomicAdd(&cnt_s[(int)(buckE[i] >> 17) - lo], 1);
  __syncthreads();
  if (t < 64) {
    int v = (t < EPB) ? cnt_s[t] : 0;
    int inc = wave_incl_scan(v, t);
    if (t < EPB) cur_s[t] = beg + inc - v;
  }
  __syncthreads();
  if (t < EPB) {
    ecnt[lo + t] = cnt_s[t];
    eoff[lo + t] = cur_s[t];
  }
  __syncthreads();
  for (int i = beg + t; i < end; i += 256) {
    unsigned u = buckE[i];
    int key = (int)(u >> 17) - lo;
    int pos = atomicAdd(&cur_s[key], 1);
    sn[pos] = (int)(u & 0x1FFFF);
  }
}

// ---------------- fused: fine_N (blocks 0..199)  ||  k_edge (blocks 200..1449) ----------------
__global__ __launch_bounds__(256) void k_edge_fineN(const unsigned* __restrict__ buckN,
                                                    const int* __restrict__ gcurn,
                                                    int* __restrict__ ncnt, int* __restrict__ noff,
                                                    int* __restrict__ se,
                                                    const unsigned char* __restrict__ mji8,
                                                    const int* __restrict__ sn,
                                                    const int* __restrict__ eoff, const int* __restrict__ ecnt,
                                                    unsigned char* __restrict__ efeat8) {
  __shared__ int cnt_s[NPB], cur_s[NPB];
  int t = threadIdx.x;
  if (blockIdx.x < NB) {
    // ---- fine_N path ----
    int b = blockIdx.x;
    int lo = b * NPB, beg = b * ECAP2, end = gcurn[b];
    for (int i = t; i < NPB; i += 256) cnt_s[i] = 0;
    __syncthreads();
    for (int i = beg + t; i < end; i += 256)
      atomicAdd(&cnt_s[(int)(buckN[i] >> 14) - lo], 1);
    __syncthreads();
    if (t < 64) {
      int carry = beg;
#pragma unroll
      for (int base = 0; base < NPB; base += 64) {
        int idx = base + t;
        int v = (idx < NPB) ? cnt_s[idx] : 0;
        int inc = wave_incl_scan(v, t);
        if (idx < NPB) cur_s[idx] = carry + inc - v;
        carry += __shfl(inc, 63, 64);
      }
    }
    __syncthreads();
    for (int i = t; i < NPB; i += 256) {
      ncnt[lo + i] = cnt_s[i];
      noff[lo + i] = cur_s[i];
    }
    __syncthreads();
    for (int i = beg + t; i < end; i += 256) {
      unsigned u = buckN[i];
      int key = (int)(u >> 14) - lo;
      int pos = atomicAdd(&cur_s[key], 1);
      se[pos] = (int)(u & 0x3FFF);
    }
  } else {
    // ---- edge path ----
    int wave = (int)(blockIdx.x - NB) * 4 + (t >> 6);
    int lane = t & 63;
    int half = lane >> 5, sub2 = (lane >> 4) & 1, c4 = lane & 15;
    int edge = wave * 2 + half;
    if (edge >= N_EDGESC) return;
    int beg = eoff[edge], cnt = ecnt[edge];
    f32x2 a0 = {0.f, 0.f}, a1 = {0.f, 0.f}, a2 = {0.f, 0.f}, a3 = {0.f, 0.f};
#pragma unroll 4
    for (int p = sub2; p < cnt; p += 2) {
      int node = sn[beg + p];
      uint2 u = ((const uint2*)(mji8 + (size_t)node * FDIM))[c4];
      a0 += __builtin_amdgcn_cvt_pk_f32_fp8(u.x, false);
      a1 += __builtin_amdgcn_cvt_pk_f32_fp8(u.x, true);
      a2 += __builtin_amdgcn_cvt_pk_f32_fp8(u.y, false);
      a3 += __builtin_amdgcn_cvt_pk_f32_fp8(u.y, true);
    }
    a0[0] += __shfl_xor(a0[0], 16, 64); a0[1] += __shfl_xor(a0[1], 16, 64);
    a1[0] += __shfl_xor(a1[0], 16, 64); a1[1] += __shfl_xor(a1[1], 16, 64);
    a2[0] += __shfl_xor(a2[0], 16, 64); a2[1] += __shfl_xor(a2[1], 16, 64);
    a3[0] += __shfl_xor(a3[0], 16, 64); a3[1] += __shfl_xor(a3[1], 16, 64);
    if (sub2 == 0) {
      float inv = 1.0f / fmaxf((float)cnt, 1.0f);
      uint2 o;
      o.x = (unsigned)__builtin_amdgcn_cvt_pk_fp8_f32(a0[0] * inv, a0[1] * inv, 0, false);
      o.x = (unsigned)__builtin_amdgcn_cvt_pk_fp8_f32(a1[0] * inv, a1[1] * inv, (int)o.x, true);
      o.y = (unsigned)__builtin_amdgcn_cvt_pk_fp8_f32(a2[0] * inv, a2[1] * inv, 0, false);
      o.y = (unsigned)__builtin_amdgcn_cvt_pk_fp8_f32(a3[0] * inv, a3[1] * inv, (int)o.y, true);
      ((uint2*)(efeat8 + (size_t)edge * FDIM))[c4] = o;
    }
  }
}

// ---------------- node reduce -> fp8 mi (one node per 16-lane sub) ----------------
__global__ __launch_bounds__(256) void k_node(const unsigned char* __restrict__ efeat8, const int* __restrict__ se,
                                              const int* __restrict__ noff, const int* __restrict__ ncnt,
                                              const float* __restrict__ recv, unsigned char* __restrict__ mi8) {
  int wave = blockIdx.x * 4 + (threadIdx.x >> 6);
  int lane = threadIdx.x & 63;
  int sub = lane >> 4, c4 = lane & 15;
  int node = wave * 4 + sub;   // 25000 waves x 4 = 100000 exactly
  int beg = noff[node], cnt = ncnt[node];
  f32x2 a0 = {0.f, 0.f}, a1 = {0.f, 0.f}, a2 = {0.f, 0.f}, a3 = {0.f, 0.f};
#pragma unroll 4
  for (int p = 0; p < cnt; p++) {
    int e = se[beg + p];
    uint2 u = ((const uint2*)(efeat8 + (size_t)e * FDIM))[c4];
    a0 += __builtin_amdgcn_cvt_pk_f32_fp8(u.x, false);
    a1 += __builtin_amdgcn_cvt_pk_f32_fp8(u.x, true);
    a2 += __builtin_amdgcn_cvt_pk_f32_fp8(u.y, false);
    a3 += __builtin_amdgcn_cvt_pk_f32_fp8(u.y, true);
  }
  float s = recv[node] / fmaxf((float)cnt, 1.0f);
  uint2 o;
  o.x = (unsigned)__builtin_amdgcn_cvt_pk_fp8_f32(a0[0] * s, a0[1] * s, 0, false);
  o.x = (unsigned)__builtin_amdgcn_cvt_pk_fp8_f32(a1[0] * s, a1[1] * s, (int)o.x, true);
  o.y = (unsigned)__builtin_amdgcn_cvt_pk_fp8_f32(a2[0] * s, a2[1] * s, 0, false);
  o.y = (unsigned)__builtin_amdgcn_cvt_pk_fp8_f32(a3[0] * s, a3[1] * s, (int)o.y, true);
  ((uint2*)(mi8 + (size_t)node * FDIM))[c4] = o;
}

// ---------------- GEMM 2: out = gelu(x @ Wupd^T + b + m_i) -> f32, 32 rows/wave ----------------
__global__ __launch_bounds__(256) void k_gemm_upd(const float* __restrict__ x, const short* __restrict__ wb,
                                                  const float* __restrict__ bias,
                                                  const unsigned char* __restrict__ mi8,
                                                  float* __restrict__ out) {
  int gw = (blockIdx.x * 256 + threadIdx.x) >> 6;
  int lane = threadIdx.x & 63;
  if (gw >= N_NODESC / 32) return;
  int rb = gw * 32;
  int lr = lane & 15, lg = lane >> 4;

  bf16x8 A0[4], A1[4];
  const float* xrow0 = x + (size_t)(rb + lr) * FDIM + lg * 8;
  const float* xrow1 = xrow0 + 16 * FDIM;
#pragma unroll
  for (int kk = 0; kk < 4; kk++) {
    A0[kk] = ldA(xrow0 + kk * 32);
    A1[kk] = ldA(xrow1 + kk * 32);
  }

#pragma unroll
  for (int c = 0; c < 8; c++) {
    f32x4 acc0 = {0.f, 0.f, 0.f, 0.f}, acc1 = {0.f, 0.f, 0.f, 0.f};
    const short* wrow = wb + (size_t)(16 * c + lr) * FDIM + lg * 8;
#pragma unroll
    for (int kk = 0; kk < 4; kk++) {
      bf16x8 B = *(const bf16x8*)(wrow + kk * 32);
      acc0 = __builtin_amdgcn_mfma_f32_16x16x32_bf16(A0[kk], B, acc0, 0, 0, 0);
      acc1 = __builtin_amdgcn_mfma_f32_16x16x32_bf16(A1[kk], B, acc1, 0, 0, 0);
    }
    int col = 16 * c + lr;
    float bc = bias[col];
#pragma unroll
    for (int j = 0; j < 4; j++) {
      int row0 = rb + lg * 4 + j;
      f32x2 m0 = __builtin_amdgcn_cvt_pk_f32_fp8((unsigned)mi8[(size_t)row0 * FDIM + col], false);
      f32x2 m1 = __builtin_amdgcn_cvt_pk_f32_fp8((unsigned)mi8[(size_t)(row0 + 16) * FDIM + col], false);
      float z0 = acc0[j] + bc + m0[0];
      float z1 = acc1[j] + bc + m1[0];
      __builtin_nontemporal_store(gelu_fast(z0), &out[(size_t)row0 * FDIM + col]);
      __builtin_nontemporal_store(gelu_fast(z1), &out[(size_t)(row0 + 16) * FDIM + col]);
    }
  }
}

extern "C" void kernel_launch(void* const* d_in, const int* in_sizes, int n_in,
                              void* d_out, int out_size, void* d_ws, size_t ws_size,
                              hipStream_t stream) {
  const float* x = (const float*)d_in[0];
  const float* action = (const float*)d_in[1];
  const float* wmsg = (const float*)d_in[2];
  const float* wupd = (const float*)d_in[3];
  const float* bupd = (const float*)d_in[4];
  const int* pn = (const int*)d_in[5];
  const int* pe = (const int*)d_in[6];
  float* out = (float*)d_out;

  char* p = (char*)d_ws;
  auto alloc = [&](size_t bytes) -> char* {
    char* r = p;
    p += (bytes + 255) & ~(size_t)255;
    return r;
  };
  unsigned char* mji8 = (unsigned char*)alloc((size_t)N_NODESC * FDIM);
  unsigned char* mi8 = (unsigned char*)alloc((size_t)N_NODESC * FDIM);
  unsigned char* efeat8 = (unsigned char*)alloc((size_t)N_EDGESC * FDIM);
  unsigned* buckE = (unsigned*)alloc((size_t)NB * ECAP2 * 4);
  unsigned* buckN = (unsigned*)alloc((size_t)NB * ECAP2 * 4);
  int* sn = (int*)alloc((size_t)NB * ECAP2 * 4);
  int* se = (int*)alloc((size_t)NB * ECAP2 * 4);
  short* wmsgb = (short*)alloc(FDIM * FDIM * 2);
  short* wupdb = (short*)alloc(FDIM * FDIM * 2);
  float* send = (float*)alloc(N_NODESC * 4);
  float* recv = (float*)alloc(N_NODESC * 4);
  int* ecnt = (int*)alloc(N_EDGESC * 4);
  int* eoff = (int*)alloc(N_EDGESC * 4);
  int* ncnt = (int*)alloc(N_NODESC * 4);
  int* noff = (int*)alloc(N_NODESC * 4);
  int* gcure = (int*)alloc(NB * 4);
  int* gcurn = (int*)alloc(NB * 4);

  k_prep<<<391, 256, 0, stream>>>(action, wmsg, wupd, wmsgb, wupdb, send, recv, gcure, gcurn);
  k_part_msg<<<2 * PA_NCH + MSG_BLKS, 256, 0, stream>>>(pn, pe, gcure, gcurn, buckE, buckN,
                                                        x, wmsgb, send, mji8);
  k_fine_e<<<NB, 256, 0, stream>>>(buckE, gcure, ecnt, eoff, sn);
  k_edge_fineN<<<NB + 1250, 256, 0, stream>>>(buckN, gcurn, ncnt, noff, se,
                                              mji8, sn, eoff, ecnt, efeat8);
  k_node<<<6250, 256, 0, stream>>>(efeat8, se, noff, ncnt, recv, mi8);
  k_gemm_upd<<<782, 256, 0, stream>>>(x, wupdb, bupd, mi8, out);
}